// Round 1
// baseline (7877.703 us; speedup 1.0000x reference)
//
#include <hip/hip_runtime.h>
#include <hip/hip_bf16.h>
#include <math.h>

// Problem constants
// B=512, T=16, DIN=7, D=512, L=2, H=8, HD=64, FF=2048

// ---------------------------------------------------------------------------
// Embed: h[b,d] = sum_i x_t[b,i]*ip_w[i,d] + ip_b[d] + pe[t,d]
// x_t[b,i] = y_fb[b,i-4] for i>=4 when t>0, else x[b,t,i]
// ---------------------------------------------------------------------------
__global__ __launch_bounds__(256)
void embed_k(const float* __restrict__ x, const float* __restrict__ y_fb,
             const float* __restrict__ ip_w, const float* __restrict__ ip_b,
             float* __restrict__ h, int t)
{
    int idx = blockIdx.x * 256 + threadIdx.x;      // [0, 512*512)
    int b = idx >> 9, d = idx & 511;
    int e = d & ~1;                                 // even exponent index
    float div = expf(-(float)e * (9.210340371976184f / 512.0f));
    float arg = (float)t * div;
    float pe = (d & 1) ? cosf(arg) : sinf(arg);
    float acc = ip_b[d] + pe;
    #pragma unroll
    for (int i = 0; i < 7; ++i) {
        float xi;
        if (t > 0 && i >= 4) xi = y_fb[b * 3 + (i - 4)];
        else                 xi = x[(b * 16 + t) * 7 + i];
        acc += xi * ip_w[i * 512 + d];
    }
    h[idx] = acc;
}

// ---------------------------------------------------------------------------
// Tiled fp32 GEMM: C[M,N] = A[M,K] @ W[K,N] + bias  (+ mode-specific epilogue)
// MODE 0: qkv  -> scatter q to qbuf, k/v (bf16) to caches at position t
// MODE 1: out  -> C = . + resid   (attention out proj + residual)
// MODE 2: ff1  -> C = relu(.)
// MODE 3: ff2  -> C = . + resid
// Tiles: 64x64, BK=16, 256 threads, 4x4 per thread.
// ---------------------------------------------------------------------------
template<int MODE>
__global__ __launch_bounds__(256)
void gemm_k(const float* __restrict__ A, const float* __restrict__ W,
            const float* __restrict__ bias, float* __restrict__ C,
            const float* __restrict__ resid,
            int M, int N, int K, int t,
            __hip_bfloat16* __restrict__ kc, __hip_bfloat16* __restrict__ vc,
            float* __restrict__ qbuf)
{
    __shared__ float As[16][68];   // [k][m], padded for b128-aligned reads
    __shared__ float Bs[16][64];   // [k][n]
    int tid = threadIdx.x;
    int tx = tid & 15, ty = tid >> 4;
    int n0 = blockIdx.x * 64, m0 = blockIdx.y * 64;
    float acc[4][4] = {};

    for (int k0 = 0; k0 < K; k0 += 16) {
        {   // load A tile 64x16 (row r=m, col c=k)
            int r = tid >> 4, c = tid & 15;      // 64 rows x 16 cols in 4 steps
            #pragma unroll
            for (int s = 0; s < 4; ++s)
                As[c][r + s * 16] = A[(m0 + r + s * 16) * K + k0 + c];
        }
        {   // load B tile 16x64
            int c = tid >> 6, n = tid & 63;      // 16 rows x 64 cols in 4 steps
            #pragma unroll
            for (int s = 0; s < 4; ++s)
                Bs[c + s * 4][n] = W[(k0 + c + s * 4) * N + n0 + n];
        }
        __syncthreads();
        #pragma unroll
        for (int kk = 0; kk < 16; ++kk) {
            float a[4], b[4];
            #pragma unroll
            for (int i = 0; i < 4; ++i) a[i] = As[kk][ty * 4 + i];
            #pragma unroll
            for (int j = 0; j < 4; ++j) b[j] = Bs[kk][tx * 4 + j];
            #pragma unroll
            for (int i = 0; i < 4; ++i)
                #pragma unroll
                for (int j = 0; j < 4; ++j)
                    acc[i][j] += a[i] * b[j];
        }
        __syncthreads();
    }

    #pragma unroll
    for (int i = 0; i < 4; ++i) {
        #pragma unroll
        for (int j = 0; j < 4; ++j) {
            int m = m0 + ty * 4 + i, n = n0 + tx * 4 + j;
            float v = acc[i][j] + bias[n];
            if (MODE == 0) {
                if (n < 512) {
                    qbuf[m * 512 + n] = v;
                } else if (n < 1024) {
                    int z = n - 512; int hh = z >> 6, hd = z & 63;
                    kc[((m * 8 + hh) * 16 + t) * 64 + hd] = __float2bfloat16(v);
                } else {
                    int z = n - 1024; int hh = z >> 6, hd = z & 63;
                    vc[((m * 8 + hh) * 16 + t) * 64 + hd] = __float2bfloat16(v);
                }
            } else if (MODE == 1 || MODE == 3) {
                C[m * N + n] = v + resid[m * N + n];
            } else { // MODE 2: relu
                C[m * N + n] = v > 0.0f ? v : 0.0f;
            }
        }
    }
}

// ---------------------------------------------------------------------------
// Attention: one wave per (b, head); lane = hd. Online softmax over s<=t.
// ---------------------------------------------------------------------------
__global__ __launch_bounds__(256)
void attn_k(const float* __restrict__ qbuf, const __hip_bfloat16* __restrict__ kc,
            const __hip_bfloat16* __restrict__ vc, float* __restrict__ attn_o, int t)
{
    int w = blockIdx.x * 4 + (threadIdx.x >> 6);   // [0, 4096)
    int lane = threadIdx.x & 63;
    int b = w >> 3, hh = w & 7;
    float qv = qbuf[b * 512 + hh * 64 + lane];
    const __hip_bfloat16* kp = kc + ((b * 8 + hh) * 16) * 64;
    const __hip_bfloat16* vp = vc + ((b * 8 + hh) * 16) * 64;
    float m = -1e30f, s = 0.0f, o = 0.0f;
    for (int j = 0; j <= t; ++j) {
        float p = qv * __bfloat162float(kp[j * 64 + lane]);
        #pragma unroll
        for (int off = 32; off; off >>= 1) p += __shfl_xor(p, off);
        p *= 0.125f;  // 1/sqrt(64)
        float nm = fmaxf(m, p);
        float sc = expf(m - nm);
        float e  = expf(p - nm);
        s = s * sc + e;
        o = o * sc + e * __bfloat162float(vp[j * 64 + lane]);
        m = nm;
    }
    attn_o[b * 512 + hh * 64 + lane] = o / s;
}

// ---------------------------------------------------------------------------
// LayerNorm over D=512, one block (256 threads) per row.
// ---------------------------------------------------------------------------
__global__ __launch_bounds__(256)
void ln_k(const float* __restrict__ src, const float* __restrict__ sc,
          const float* __restrict__ bi, float* __restrict__ dst)
{
    int b = blockIdx.x;
    int tid = threadIdx.x;
    __shared__ float red[4];
    float x0 = src[b * 512 + tid];
    float x1 = src[b * 512 + 256 + tid];
    float sum = x0 + x1;
    #pragma unroll
    for (int off = 32; off; off >>= 1) sum += __shfl_xor(sum, off);
    if ((tid & 63) == 0) red[tid >> 6] = sum;
    __syncthreads();
    float mean = (red[0] + red[1] + red[2] + red[3]) * (1.0f / 512.0f);
    float d0 = x0 - mean, d1 = x1 - mean;
    float vs = d0 * d0 + d1 * d1;
    #pragma unroll
    for (int off = 32; off; off >>= 1) vs += __shfl_xor(vs, off);
    __syncthreads();
    if ((tid & 63) == 0) red[tid >> 6] = vs;
    __syncthreads();
    float var = (red[0] + red[1] + red[2] + red[3]) * (1.0f / 512.0f);
    float r = rsqrtf(var + 1e-5f);
    dst[b * 512 + tid]       = d0 * r * sc[tid]       + bi[tid];
    dst[b * 512 + 256 + tid] = d1 * r * sc[256 + tid] + bi[256 + tid];
}

// ---------------------------------------------------------------------------
// Head: y[b,:] = h[b,:] @ head_w + head_b ; write to out[:,t,:] and feedback.
// One wave per row b.
// ---------------------------------------------------------------------------
__global__ __launch_bounds__(256)
void head_k(const float* __restrict__ h, const float* __restrict__ hw,
            const float* __restrict__ hb, float* __restrict__ out,
            float* __restrict__ y_fb, int t)
{
    int b = blockIdx.x * 4 + (threadIdx.x >> 6);
    int lane = threadIdx.x & 63;
    float a0 = 0.0f, a1 = 0.0f, a2 = 0.0f;
    #pragma unroll
    for (int i = 0; i < 8; ++i) {
        int d = lane + i * 64;
        float hv = h[b * 512 + d];
        a0 += hv * hw[d * 3 + 0];
        a1 += hv * hw[d * 3 + 1];
        a2 += hv * hw[d * 3 + 2];
    }
    #pragma unroll
    for (int off = 32; off; off >>= 1) {
        a0 += __shfl_xor(a0, off);
        a1 += __shfl_xor(a1, off);
        a2 += __shfl_xor(a2, off);
    }
    if (lane == 0) {
        float y0 = a0 + hb[0], y1 = a1 + hb[1], y2 = a2 + hb[2];
        out[(b * 16 + t) * 3 + 0] = y0;
        out[(b * 16 + t) * 3 + 1] = y1;
        out[(b * 16 + t) * 3 + 2] = y2;
        y_fb[b * 3 + 0] = y0;
        y_fb[b * 3 + 1] = y1;
        y_fb[b * 3 + 2] = y2;
    }
}

// ---------------------------------------------------------------------------
extern "C" void kernel_launch(void* const* d_in, const int* in_sizes, int n_in,
                              void* d_out, int out_size, void* d_ws, size_t ws_size,
                              hipStream_t stream)
{
    const float* x     = (const float*)d_in[0];
    const float* ip_w  = (const float*)d_in[1];
    const float* ip_b  = (const float*)d_in[2];
    const float* qkv_w = (const float*)d_in[3];
    const float* qkv_b = (const float*)d_in[4];
    const float* out_w = (const float*)d_in[5];
    const float* out_b = (const float*)d_in[6];
    const float* ln1_s = (const float*)d_in[7];
    const float* ln1_b = (const float*)d_in[8];
    const float* ff_w1 = (const float*)d_in[9];
    const float* ff_b1 = (const float*)d_in[10];
    const float* ff_w2 = (const float*)d_in[11];
    const float* ff_b2 = (const float*)d_in[12];
    const float* ln2_s = (const float*)d_in[13];
    const float* ln2_b = (const float*)d_in[14];
    const float* hw    = (const float*)d_in[15];
    const float* hb    = (const float*)d_in[16];
    float* out = (float*)d_out;

    // Workspace layout (floats then bf16 caches); total ~40 MB
    float* h      = (float*)d_ws;          // 262144
    float* tmp    = h      + 262144;       // 262144
    float* qbuf   = tmp    + 262144;       // 262144
    float* attn_o = qbuf   + 262144;       // 262144
    float* ff     = attn_o + 262144;       // 1048576
    float* y_fb   = ff     + 1048576;      // 1536 (padded to 2048)
    __hip_bfloat16* kc = (__hip_bfloat16*)(y_fb + 2048);  // L*B*H*T*HD = 8388608
    __hip_bfloat16* vc = kc + 8388608;

    const int CPL = 512 * 8 * 16 * 64;     // cache elems per layer = 4194304

    for (int t = 0; t < 16; ++t) {
        embed_k<<<1024, 256, 0, stream>>>(x, y_fb, ip_w, ip_b, h, t);
        for (int l = 0; l < 2; ++l) {
            // QKV: [512,512] @ [512,1536]
            gemm_k<0><<<dim3(24, 8), 256, 0, stream>>>(
                h, qkv_w + l * 786432, qkv_b + l * 1536,
                nullptr, nullptr, 512, 1536, 512, t,
                kc + l * CPL, vc + l * CPL, qbuf);
            // Attention over cached positions 0..t
            attn_k<<<1024, 256, 0, stream>>>(qbuf, kc + l * CPL, vc + l * CPL, attn_o, t);
            // Out-proj + residual: [512,512] @ [512,512]
            gemm_k<1><<<dim3(8, 8), 256, 0, stream>>>(
                attn_o, out_w + l * 262144, out_b + l * 512,
                tmp, h, 512, 512, 512, t, nullptr, nullptr, nullptr);
            ln_k<<<512, 256, 0, stream>>>(tmp, ln1_s + l * 512, ln1_b + l * 512, h);
            // FF1 + relu: [512,512] @ [512,2048]
            gemm_k<2><<<dim3(32, 8), 256, 0, stream>>>(
                h, ff_w1 + l * 1048576, ff_b1 + l * 2048,
                ff, nullptr, 512, 2048, 512, t, nullptr, nullptr, nullptr);
            // FF2 + residual: [512,2048] @ [2048,512]
            gemm_k<3><<<dim3(8, 8), 256, 0, stream>>>(
                ff, ff_w2 + l * 1048576, ff_b2 + l * 512,
                tmp, h, 512, 512, 2048, t, nullptr, nullptr, nullptr);
            ln_k<<<512, 256, 0, stream>>>(tmp, ln2_s + l * 512, ln2_b + l * 512, h);
        }
        head_k<<<128, 256, 0, stream>>>(h, hw, hb, out, y_fb, t);
    }
}

// Round 2
// 2363.449 us; speedup vs baseline: 3.3331x; 3.3331x over previous
//
#include <hip/hip_runtime.h>
#include <hip/hip_bf16.h>
#include <math.h>

// B=512, T=16, DIN=7, D=512, L=2, H=8, HD=64, FF=2048
// Incremental KV-cached decode; bf16 MFMA GEMMs with fp32 accumulate.

typedef __attribute__((__ext_vector_type__(8))) short short8;
typedef __attribute__((__ext_vector_type__(4))) float floatx4;

__device__ inline short8 as_short8(uint4 v){ union U{uint4 u; short8 s;} x; x.u=v; return x.s; }

__device__ inline ushort f2bf(float f){
    __hip_bfloat16 h = __float2bfloat16(f);
    ushort u; __builtin_memcpy(&u, &h, 2); return u;
}

// ---------------------------------------------------------------------------
// Weight swizzle: fp32 W[K][N] -> bf16 16B groups of 8 k-consecutive values.
// Group linear index = (kb*4 + q)*N + n, holding W[kb*32+q*8 .. +7][n].
// blockIdx.z = matrix id: (mi = z>>1) 0:qkv 1:out 2:ff1 3:ff2, l = z&1.
// ---------------------------------------------------------------------------
__global__ __launch_bounds__(256)
void swz_k(const float* __restrict__ qkv_w, const float* __restrict__ out_w,
           const float* __restrict__ ff1_w, const float* __restrict__ ff2_w,
           ushort* __restrict__ wsw)
{
    int id = blockIdx.z; int l = id & 1; int mi = id >> 1;
    int K, N; const float* src; size_t doff;
    if (mi == 0)      { K = 512;  N = 1536; src = qkv_w + (size_t)l*786432;  doff = (size_t)l*786432; }
    else if (mi == 1) { K = 512;  N = 512;  src = out_w + (size_t)l*262144;  doff = 1572864 + (size_t)l*262144; }
    else if (mi == 2) { K = 512;  N = 2048; src = ff1_w + (size_t)l*1048576; doff = 2097152 + (size_t)l*1048576; }
    else              { K = 2048; N = 512;  src = ff2_w + (size_t)l*1048576; doff = 4194304 + (size_t)l*1048576; }
    int n0 = blockIdx.x * 64, k0 = blockIdx.y * 32;
    if (n0 >= N || k0 >= K) return;
    __shared__ float tt[32][64];
    int tid = threadIdx.x;
    int c = tid & 63, r = tid >> 6;
    #pragma unroll
    for (int i = 0; i < 8; ++i)
        tt[r + i*4][c] = src[(size_t)(k0 + r + i*4)*N + n0 + c];
    __syncthreads();
    int q = tid >> 6, n = tid & 63;
    union { ushort s[8]; uint4 v; } pk;
    #pragma unroll
    for (int i = 0; i < 8; ++i) pk.s[i] = f2bf(tt[q*8 + i][n]);
    ((uint4*)(wsw + doff))[(size_t)((k0 >> 5)*4 + q)*N + n0 + n] = pk.v;
}

// ---------------------------------------------------------------------------
// Initial embed (t=0): h = x@ip_w + ip_b + pe[0]; writes fp32 + bf16 copies.
// ---------------------------------------------------------------------------
__global__ __launch_bounds__(256)
void embed0_k(const float* __restrict__ x, const float* __restrict__ ip_w,
              const float* __restrict__ ip_b, float* __restrict__ h,
              __hip_bfloat16* __restrict__ hbf)
{
    int idx = blockIdx.x*256 + threadIdx.x;   // [0, 512*512)
    int b = idx >> 9, d = idx & 511;
    float pe = (d & 1) ? 1.0f : 0.0f;         // t=0: sin(0)=0, cos(0)=1
    float acc = ip_b[d] + pe;
    #pragma unroll
    for (int i = 0; i < 7; ++i)
        acc += x[(b*16 + 0)*7 + i] * ip_w[i*512 + d];
    h[idx] = acc;
    hbf[idx] = __float2bfloat16(acc);
}

// ---------------------------------------------------------------------------
// MFMA GEMM, tiled 64x64, 4 waves (each 32x32 = 2x2 tiles of 16x16x32).
// MODE 0: QKV (N=1536,K=512): scatter q->qbuf fp32, k/v->bf16 caches at pos t
// MODE 1: FF1 (N=2048,K=512): relu -> bf16
// MODE 2: FF2 (N=512,K=2048): + resid -> fp32 tmp
// ---------------------------------------------------------------------------
template<int MODE>
__global__ __launch_bounds__(256)
void gemm64_k(const __hip_bfloat16* __restrict__ A, const ushort* __restrict__ Wsw,
              const float* __restrict__ bias, int t,
              float* __restrict__ qbuf, __hip_bfloat16* __restrict__ kc,
              __hip_bfloat16* __restrict__ vc,
              __hip_bfloat16* __restrict__ obf, float* __restrict__ ofp,
              const float* __restrict__ resid)
{
    constexpr int K = (MODE == 2) ? 2048 : 512;
    constexpr int N = (MODE == 0) ? 1536 : (MODE == 1 ? 2048 : 512);
    __shared__ uint4 ldsA[256], ldsB[256];
    int tid = threadIdx.x, lane = tid & 63, w = tid >> 6;
    int n0 = blockIdx.x*64, m0 = blockIdx.y*64;
    const uint4* Ag = (const uint4*)A;
    const uint4* Bg = (const uint4*)Wsw;
    int am = tid >> 2, aq = tid & 3;
    int bq = tid >> 6, bn = tid & 63;
    int rh = w & 1, ch = w >> 1;
    int qd = lane >> 4, ln = lane & 15;
    floatx4 a00 = {}, a01 = {}, a10 = {}, a11 = {};
    for (int kb = 0; kb < K/32; ++kb){
        ldsA[aq*64 + am] = Ag[(size_t)(m0 + am)*(K/8) + kb*4 + aq];
        ldsB[bq*64 + bn] = Bg[(size_t)(kb*4 + bq)*N + n0 + bn];
        __syncthreads();
        short8 af0 = as_short8(ldsA[qd*64 + rh*32 +      ln]);
        short8 af1 = as_short8(ldsA[qd*64 + rh*32 + 16 + ln]);
        short8 bf0 = as_short8(ldsB[qd*64 + ch*32 +      ln]);
        short8 bf1 = as_short8(ldsB[qd*64 + ch*32 + 16 + ln]);
        a00 = __builtin_amdgcn_mfma_f32_16x16x32_bf16(af0, bf0, a00, 0, 0, 0);
        a01 = __builtin_amdgcn_mfma_f32_16x16x32_bf16(af0, bf1, a01, 0, 0, 0);
        a10 = __builtin_amdgcn_mfma_f32_16x16x32_bf16(af1, bf0, a10, 0, 0, 0);
        a11 = __builtin_amdgcn_mfma_f32_16x16x32_bf16(af1, bf1, a11, 0, 0, 0);
        __syncthreads();
    }
    floatx4 accs[2][2] = {{a00, a01}, {a10, a11}};
    #pragma unroll
    for (int i = 0; i < 2; ++i){
        #pragma unroll
        for (int j = 0; j < 2; ++j){
            #pragma unroll
            for (int r = 0; r < 4; ++r){
                int m = m0 + rh*32 + i*16 + qd*4 + r;
                int n = n0 + ch*32 + j*16 + ln;
                float v = accs[i][j][r] + bias[n];
                if (MODE == 0){
                    if (n < 512) qbuf[(size_t)m*512 + n] = v;
                    else if (n < 1024){ int z = n - 512;
                        kc[(((size_t)m*8 + (z >> 6))*16 + t)*64 + (z & 63)] = __float2bfloat16(v); }
                    else { int z = n - 1024;
                        vc[(((size_t)m*8 + (z >> 6))*16 + t)*64 + (z & 63)] = __float2bfloat16(v); }
                } else if (MODE == 1){
                    obf[(size_t)m*2048 + n] = __float2bfloat16(fmaxf(v, 0.0f));
                } else {
                    ofp[(size_t)m*512 + n] = v + resid[(size_t)m*512 + n];
                }
            }
        }
    }
}

// ---------------------------------------------------------------------------
// Attention: one wave per (b, head); lane = hd. Online softmax over s<=t.
// ---------------------------------------------------------------------------
__global__ __launch_bounds__(256)
void attn_k(const float* __restrict__ qbuf, const __hip_bfloat16* __restrict__ kc,
            const __hip_bfloat16* __restrict__ vc, __hip_bfloat16* __restrict__ attn_o, int t)
{
    int w = blockIdx.x*4 + (threadIdx.x >> 6);
    int lane = threadIdx.x & 63;
    int b = w >> 3, hh = w & 7;
    float qv = qbuf[(size_t)b*512 + hh*64 + lane];
    const __hip_bfloat16* kp = kc + ((size_t)b*8 + hh)*16*64;
    const __hip_bfloat16* vp = vc + ((size_t)b*8 + hh)*16*64;
    float m = -1e30f, s = 0.0f, o = 0.0f;
    for (int j = 0; j <= t; ++j){
        float p = qv * __bfloat162float(kp[j*64 + lane]);
        #pragma unroll
        for (int off = 32; off; off >>= 1) p += __shfl_xor(p, off);
        p *= 0.125f;
        float nm = fmaxf(m, p);
        float sc = expf(m - nm);
        float e  = expf(p - nm);
        s = s*sc + e;
        o = o*sc + e*__bfloat162float(vp[j*64 + lane]);
        m = nm;
    }
    attn_o[(size_t)b*512 + hh*64 + lane] = __float2bfloat16(o / s);
}

// ---------------------------------------------------------------------------
// Fused out-proj + bias + residual + LN1. Full-row blocks: 16 rows x 512 cols.
// A slab staged in LDS once; B fragments loaded directly from global.
// ---------------------------------------------------------------------------
__global__ __launch_bounds__(256)
void outln_k(const __hip_bfloat16* __restrict__ Abf, const ushort* __restrict__ Wsw,
             const float* __restrict__ ob, const float* __restrict__ g,
             const float* __restrict__ be, float* __restrict__ h,
             __hip_bfloat16* __restrict__ hbf)
{
    __shared__ uint4 lA[64*17 + 1];
    __shared__ float redS[4][4][4], redQ[4][4][4];
    int tid = threadIdx.x, lane = tid & 63, w = tid >> 6;
    int m0 = blockIdx.x*16;
    const uint4* Ag = (const uint4*)Abf;
    #pragma unroll
    for (int it = 0; it < 4; ++it){
        int m = it*4 + w;
        lA[lane*17 + m] = Ag[(size_t)(m0 + m)*64 + lane];   // group (kb*4+q)=lane
    }
    __syncthreads();
    const uint4* Bg = (const uint4*)Wsw;
    int qd = lane >> 4, ln = lane & 15;
    floatx4 acc[8] = {};
    for (int kb = 0; kb < 16; ++kb){
        short8 af = as_short8(lA[(kb*4 + qd)*17 + ln]);
        #pragma unroll
        for (int c = 0; c < 8; ++c){
            int n = w*128 + c*16 + ln;
            short8 bf = as_short8(Bg[(size_t)(kb*4 + qd)*512 + n]);
            acc[c] = __builtin_amdgcn_mfma_f32_16x16x32_bf16(af, bf, acc[c], 0, 0, 0);
        }
    }
    float v[8][4];
    float psum[4] = {}, psq[4] = {};
    #pragma unroll
    for (int c = 0; c < 8; ++c){
        #pragma unroll
        for (int r = 0; r < 4; ++r){
            int m = qd*4 + r, n = w*128 + c*16 + ln;
            float xv = acc[c][r] + ob[n] + h[(size_t)(m0 + m)*512 + n];
            v[c][r] = xv; psum[r] += xv; psq[r] += xv*xv;
        }
    }
    #pragma unroll
    for (int off = 1; off < 16; off <<= 1){
        #pragma unroll
        for (int r = 0; r < 4; ++r){ psum[r] += __shfl_xor(psum[r], off); psq[r] += __shfl_xor(psq[r], off); }
    }
    if (ln == 0){
        #pragma unroll
        for (int r = 0; r < 4; ++r){ redS[w][qd][r] = psum[r]; redQ[w][qd][r] = psq[r]; }
    }
    __syncthreads();
    float mean[4], rstd[4];
    #pragma unroll
    for (int r = 0; r < 4; ++r){
        float sm = redS[0][qd][r] + redS[1][qd][r] + redS[2][qd][r] + redS[3][qd][r];
        float sq = redQ[0][qd][r] + redQ[1][qd][r] + redQ[2][qd][r] + redQ[3][qd][r];
        mean[r] = sm * (1.0f/512.0f);
        float var = sq * (1.0f/512.0f) - mean[r]*mean[r];
        rstd[r] = rsqrtf(var + 1e-5f);
    }
    #pragma unroll
    for (int c = 0; c < 8; ++c){
        #pragma unroll
        for (int r = 0; r < 4; ++r){
            int m = qd*4 + r, n = w*128 + c*16 + ln;
            float hn = (v[c][r] - mean[r])*rstd[r]*g[n] + be[n];
            h[(size_t)(m0 + m)*512 + n] = hn;
            hbf[(size_t)(m0 + m)*512 + n] = __float2bfloat16(hn);
        }
    }
}

// ---------------------------------------------------------------------------
// Fused LN2 (+ head + next-step embed when dohead). One block per row.
// tmp already holds ff2-out + bias + residual.
// ---------------------------------------------------------------------------
__global__ __launch_bounds__(256)
void ln2he_k(const float* __restrict__ tmp, const float* __restrict__ g,
             const float* __restrict__ be, float* __restrict__ h,
             __hip_bfloat16* __restrict__ hbf,
             const float* __restrict__ hw, const float* __restrict__ hb,
             const float* __restrict__ x, const float* __restrict__ ip_w,
             const float* __restrict__ ip_b, float* __restrict__ out,
             int t, int dohead)
{
    int b = blockIdx.x, tid = threadIdx.x;
    __shared__ float red[4];
    __shared__ float hred[4][3];
    __shared__ float ybc[3];
    float x0 = tmp[(size_t)b*512 + tid];
    float x1 = tmp[(size_t)b*512 + 256 + tid];
    float s = x0 + x1;
    #pragma unroll
    for (int off = 32; off; off >>= 1) s += __shfl_xor(s, off);
    if ((tid & 63) == 0) red[tid >> 6] = s;
    __syncthreads();
    float mean = (red[0] + red[1] + red[2] + red[3]) * (1.0f/512.0f);
    float d0 = x0 - mean, d1 = x1 - mean;
    float vs = d0*d0 + d1*d1;
    #pragma unroll
    for (int off = 32; off; off >>= 1) vs += __shfl_xor(vs, off);
    __syncthreads();
    if ((tid & 63) == 0) red[tid >> 6] = vs;
    __syncthreads();
    float var = (red[0] + red[1] + red[2] + red[3]) * (1.0f/512.0f);
    float r = rsqrtf(var + 1e-5f);
    float n0_ = d0*r*g[tid]       + be[tid];
    float n1_ = d1*r*g[256 + tid] + be[256 + tid];
    if (!dohead){
        h[(size_t)b*512 + tid] = n0_;
        h[(size_t)b*512 + 256 + tid] = n1_;
        hbf[(size_t)b*512 + tid] = __float2bfloat16(n0_);
        hbf[(size_t)b*512 + 256 + tid] = __float2bfloat16(n1_);
        return;
    }
    float s0 = n0_*hw[tid*3]     + n1_*hw[(tid+256)*3];
    float s1 = n0_*hw[tid*3 + 1] + n1_*hw[(tid+256)*3 + 1];
    float s2 = n0_*hw[tid*3 + 2] + n1_*hw[(tid+256)*3 + 2];
    #pragma unroll
    for (int off = 32; off; off >>= 1){
        s0 += __shfl_xor(s0, off); s1 += __shfl_xor(s1, off); s2 += __shfl_xor(s2, off);
    }
    int w = tid >> 6;
    if ((tid & 63) == 0){ hred[w][0] = s0; hred[w][1] = s1; hred[w][2] = s2; }
    __syncthreads();
    if (tid < 3){
        float y = hred[0][tid] + hred[1][tid] + hred[2][tid] + hred[3][tid] + hb[tid];
        out[((size_t)b*16 + t)*3 + tid] = y;
        ybc[tid] = y;
    }
    __syncthreads();
    if (t < 15){
        float y0 = ybc[0], y1 = ybc[1], y2 = ybc[2];
        #pragma unroll
        for (int half = 0; half < 2; ++half){
            int d = tid + half*256;
            int e = d & ~1;
            float div = expf(-(float)e * (9.210340371976184f / 512.0f));
            float arg = (float)(t + 1) * div;
            float pe = (d & 1) ? cosf(arg) : sinf(arg);
            float acc = ip_b[d] + pe;
            #pragma unroll
            for (int i = 0; i < 4; ++i)
                acc += x[((size_t)b*16 + t + 1)*7 + i] * ip_w[i*512 + d];
            acc += y0*ip_w[4*512 + d] + y1*ip_w[5*512 + d] + y2*ip_w[6*512 + d];
            h[(size_t)b*512 + d] = acc;
            hbf[(size_t)b*512 + d] = __float2bfloat16(acc);
        }
    }
}

// ---------------------------------------------------------------------------
extern "C" void kernel_launch(void* const* d_in, const int* in_sizes, int n_in,
                              void* d_out, int out_size, void* d_ws, size_t ws_size,
                              hipStream_t stream)
{
    const float* x     = (const float*)d_in[0];
    const float* ip_w  = (const float*)d_in[1];
    const float* ip_b  = (const float*)d_in[2];
    const float* qkv_w = (const float*)d_in[3];
    const float* qkv_b = (const float*)d_in[4];
    const float* out_w = (const float*)d_in[5];
    const float* out_b = (const float*)d_in[6];
    const float* ln1_s = (const float*)d_in[7];
    const float* ln1_b = (const float*)d_in[8];
    const float* ff_w1 = (const float*)d_in[9];
    const float* ff_b1 = (const float*)d_in[10];
    const float* ff_w2 = (const float*)d_in[11];
    const float* ff_b2 = (const float*)d_in[12];
    const float* ln2_s = (const float*)d_in[13];
    const float* ln2_b = (const float*)d_in[14];
    const float* hw    = (const float*)d_in[15];
    const float* hb    = (const float*)d_in[16];
    float* out = (float*)d_out;

    // ws layout (bytes): wsw 12582912 | h 1MB | tmp 1MB | qbuf 1MB | hbf 512K
    //                    attnbf 512K | ffbf 2MB | kc 16MB | vc 16MB  = 50 MB
    ushort* wsw = (ushort*)d_ws;
    float* h    = (float*)((char*)d_ws + 12582912);
    float* tmp  = h + 262144;
    float* qbuf = tmp + 262144;
    __hip_bfloat16* hbf    = (__hip_bfloat16*)(qbuf + 262144);
    __hip_bfloat16* attnbf = hbf + 262144;
    __hip_bfloat16* ffbf   = attnbf + 262144;
    __hip_bfloat16* kc     = ffbf + 1048576;
    __hip_bfloat16* vc     = kc + 8388608;
    const int CPL = 4194304;   // kv-cache elems per layer

    swz_k<<<dim3(32, 64, 8), 256, 0, stream>>>(qkv_w, out_w, ff_w1, ff_w2, wsw);
    embed0_k<<<1024, 256, 0, stream>>>(x, ip_w, ip_b, h, hbf);

    for (int t = 0; t < 16; ++t){
        for (int l = 0; l < 2; ++l){
            gemm64_k<0><<<dim3(24, 8), 256, 0, stream>>>(
                hbf, wsw + (size_t)l*786432, qkv_b + l*1536, t,
                qbuf, kc + (size_t)l*CPL, vc + (size_t)l*CPL,
                nullptr, nullptr, nullptr);
            attn_k<<<1024, 256, 0, stream>>>(qbuf, kc + (size_t)l*CPL, vc + (size_t)l*CPL, attnbf, t);
            outln_k<<<32, 256, 0, stream>>>(
                attnbf, wsw + 1572864 + (size_t)l*262144, out_b + l*512,
                ln1_s + l*512, ln1_b + l*512, h, hbf);
            gemm64_k<1><<<dim3(32, 8), 256, 0, stream>>>(
                hbf, wsw + 2097152 + (size_t)l*1048576, ff_b1 + l*2048, t,
                nullptr, nullptr, nullptr, ffbf, nullptr, nullptr);
            gemm64_k<2><<<dim3(8, 8), 256, 0, stream>>>(
                ffbf, wsw + 4194304 + (size_t)l*1048576, ff_b2 + l*512, t,
                nullptr, nullptr, nullptr, nullptr, tmp, h);
            ln2he_k<<<512, 256, 0, stream>>>(
                tmp, ln2_s + l*512, ln2_b + l*512, h, hbf,
                hw, hb, x, ip_w, ip_b, out, t, l == 1);
        }
    }
}